// Round 2
// baseline (245.369 us; speedup 1.0000x reference)
//
#include <hip/hip_runtime.h>
#include <hip/hip_bf16.h>

// B=8, L=4096, C=384, h=8, d=48, H=W=64
// Inputs/outputs fp32 (per reference). Internals: weights pre-converted to
// bf16 (ws), qkv/y bf16 (ws), sumsq/G/attn2 fp32 (ws).
// x fp32->bf16 conversion is fused into the qkv GEMM's A-staging.

typedef __bf16 bf16x8 __attribute__((ext_vector_type(8)));
typedef float f32x4 __attribute__((ext_vector_type(4)));

__device__ inline __bf16 f2b(float f) {
    __hip_bfloat16 h = __float2bfloat16(f);
    __bf16 r; __builtin_memcpy(&r, &h, 2); return r;
}
__device__ inline float b2f(__hip_bfloat16 h) { return __bfloat162float(h); }
__device__ inline float b2f(__bf16 v) {
    __hip_bfloat16 h; __builtin_memcpy(&h, &v, 2); return __bfloat162float(h);
}

__device__ inline bf16x8 load8(const __hip_bfloat16* p) {
    uint4 v = *(const uint4*)p;
    bf16x8 r; __builtin_memcpy(&r, &v, 16); return r;
}
__device__ inline bf16x8 load8(const float* p) {
    float4 a = *(const float4*)p;
    float4 b = *(const float4*)(p + 4);
    bf16x8 r;
    r[0] = f2b(a.x); r[1] = f2b(a.y); r[2] = f2b(a.z); r[3] = f2b(a.w);
    r[4] = f2b(b.x); r[5] = f2b(b.y); r[6] = f2b(b.z); r[7] = f2b(b.w);
    return r;
}

__device__ inline void storef(float* p, float v) { *p = v; }
__device__ inline void storef(__hip_bfloat16* p, float v) { *p = __float2bfloat16(v); }

// async 16B global -> LDS (wave-uniform base + lane*16 dest required)
__device__ inline void gl_lds16(const __hip_bfloat16* g, __hip_bfloat16* l) {
    __builtin_amdgcn_global_load_lds(
        (const __attribute__((address_space(1))) void*)g,
        (__attribute__((address_space(3))) void*)l,
        16, 0, 0);
}

// ---------------------------------------------------------------------------
// fp32 -> bf16 conversion: qkv_w (216 blocks), proj_w (72) — weights only.
// ---------------------------------------------------------------------------
__global__ __launch_bounds__(256) void cvt_kernel(
    const float* __restrict__ qw, __hip_bfloat16* __restrict__ qwb,
    const float* __restrict__ pw, __hip_bfloat16* __restrict__ pwb)
{
    int blk = blockIdx.x;
    const float* src; __hip_bfloat16* dst; int base;
    if (blk < 216) { src = qw; dst = qwb; base = blk; }
    else           { src = pw; dst = pwb; base = blk - 216; }
    int i = base * 256 + threadIdx.x;
    bf16x8 v = load8(src + (size_t)i * 8);
    *(bf16x8*)(dst + (size_t)i * 8) = v;
}

// ---------------------------------------------------------------------------
// GEMM: C[M,N] = A[M,K] @ Bw[N,K]^T + bias[N], fp32 accum.
// Block tile 128x64, BK=64, 6 k-iters (K=384). 4 waves, each 64x32
// (4x2 MFMA 16x16x32, 32 AGPR acc -> ~6 blocks/CU residency).
// A is either bf16 (async global_load_lds staging) or fp32 (fused convert:
// load fp32 -> cvt -> ds_write_b128 into the SAME swizzled LDS layout).
// B staged via global_load_lds width-16; the GLOBAL source chunk is
// XOR-swizzled (chunk ^ (row&7)) so the logical LDS layout is
// bank-conflict-free on ds_read_b128 fragment reads.
// 1-D grid, XCD swizzle: all NXT col-tiles of one row-tile on one XCD.
// Optional fused column sum-of-squares (cols < 768) into sq via atomics.
// ---------------------------------------------------------------------------
template <typename TA, typename TO, int KC, bool FUSE_SQ>
__global__ __launch_bounds__(256) void gemm_bf16_nt(
    const TA* __restrict__ A,
    const __hip_bfloat16* __restrict__ Bw,
    const float* __restrict__ bias,
    TO* __restrict__ C,
    int N, int NXT,
    float* __restrict__ sq)
{
    __shared__ __hip_bfloat16 As[128 * 64];   // 16 KB
    __shared__ __hip_bfloat16 Bs[64 * 64];    //  8 KB
    const int t = threadIdx.x;
    const int w = t >> 6, lane = t & 63;
    const int r16 = lane & 15, quad = lane >> 4;
    const int bx  = blockIdx.x;
    const int xcd = bx & 7, seq = bx >> 3;
    const int n_t = seq % NXT, m_t = seq / NXT;
    const int m0 = (xcd + 8 * m_t) * 128;
    const int n0 = n_t * 64;
    const int wm = w >> 1, wn = w & 1;

    f32x4 acc[4][2];
    #pragma unroll
    for (int mi = 0; mi < 4; ++mi)
        #pragma unroll
        for (int ni = 0; ni < 2; ++ni)
            acc[mi][ni] = (f32x4){0.f, 0.f, 0.f, 0.f};

    for (int k0 = 0; k0 < KC; k0 += 64) {
        // B first (async, in flight while A stages): wave w stages rows
        // [w*16, w*16+16), 2 chunks/lane.
        #pragma unroll
        for (int p = 0; p < 2; ++p) {
            int c = p * 64 + lane;                    // 0..127
            int rl = c >> 3;                          // row within wave's 16
            int cc = (c & 7) ^ (rl & 7);
            gl_lds16(Bw + (size_t)(n0 + w * 16 + rl) * KC + k0 + cc * 8,
                     &Bs[(w * 128 + c) * 8]);
        }
        // A: wave w stages rows [w*32, w*32+32), 8 chunks(16B)/row, 4/lane.
        // LDS dest chunk P = w*256 + p*64 + lane (contiguous); global source
        // column-chunk = (P&7) ^ (row&7)  [XOR swizzle].
        if constexpr (__is_same(TA, float)) {
            // fused fp32->bf16: load 8 floats, convert, ds_write_b128.
            #pragma unroll
            for (int p = 0; p < 4; ++p) {
                int c = p * 64 + lane;                // 0..255
                int rl = c >> 3;                      // row within wave's 32
                int cc = (c & 7) ^ (rl & 7);
                const float* src = A + (size_t)(m0 + w * 32 + rl) * KC + k0 + cc * 8;
                float4 a = *(const float4*)src;
                float4 b = *(const float4*)(src + 4);
                bf16x8 r;
                r[0] = f2b(a.x); r[1] = f2b(a.y); r[2] = f2b(a.z); r[3] = f2b(a.w);
                r[4] = f2b(b.x); r[5] = f2b(b.y); r[6] = f2b(b.z); r[7] = f2b(b.w);
                *(bf16x8*)&As[(w * 256 + c) * 8] = r;
            }
        } else {
            #pragma unroll
            for (int p = 0; p < 4; ++p) {
                int c = p * 64 + lane;                // 0..255
                int rl = c >> 3;
                int cc = (c & 7) ^ (rl & 7);
                gl_lds16(A + (size_t)(m0 + w * 32 + rl) * KC + k0 + cc * 8,
                         &As[(w * 256 + c) * 8]);
            }
        }
        __syncthreads();   // drains vmcnt (incl. global_load_lds) + lgkm
        bf16x8 af[4][2], bfr[2][2];
        #pragma unroll
        for (int ks = 0; ks < 2; ++ks) {
            #pragma unroll
            for (int mi = 0; mi < 4; ++mi) {
                int row = wm * 64 + mi * 16 + r16;
                int pc  = (ks * 4 + quad) ^ (r16 & 7);   // physical chunk
                af[mi][ks] = *(const bf16x8*)&As[row * 64 + pc * 8];
            }
            #pragma unroll
            for (int ni = 0; ni < 2; ++ni) {
                int row = wn * 32 + ni * 16 + r16;
                int pc  = (ks * 4 + quad) ^ (r16 & 7);
                bfr[ni][ks] = *(const bf16x8*)&Bs[row * 64 + pc * 8];
            }
        }
        #pragma unroll
        for (int ks = 0; ks < 2; ++ks)
            #pragma unroll
            for (int mi = 0; mi < 4; ++mi)
                #pragma unroll
                for (int ni = 0; ni < 2; ++ni)
                    acc[mi][ni] = __builtin_amdgcn_mfma_f32_16x16x32_bf16(
                        af[mi][ks], bfr[ni][ks], acc[mi][ni], 0, 0, 0);
        __syncthreads();
    }

    #pragma unroll
    for (int ni = 0; ni < 2; ++ni) {
        int col = n0 + wn * 32 + ni * 16 + r16;
        float bv = bias[col];
        float s = 0.f;
        #pragma unroll
        for (int mi = 0; mi < 4; ++mi) {
            #pragma unroll
            for (int reg = 0; reg < 4; ++reg) {
                int row = m0 + wm * 64 + mi * 16 + quad * 4 + reg;
                float o = acc[mi][ni][reg] + bv;
                storef(&C[(size_t)row * N + col], o);
                s += o * o;
            }
        }
        if constexpr (FUSE_SQ) {
            if (col < 768) {
                s += __shfl_xor(s, 16);
                s += __shfl_xor(s, 32);
                if (quad == 0) {
                    int b = m0 >> 12;   // 4096 rows per batch
                    atomicAdd(&sq[b * 768 + col], s);
                }
            }
        }
    }
}

// ---------------------------------------------------------------------------
// G[bh] = k^T v  via MFMA.  Grid (16, 64): each block covers 256 of L for one
// (b,h) -> 1024 blocks (~4/CU for latency hiding). 4 waves on disjoint 32-l
// chunks; k,v tiles staged TRANSPOSED in LDS.
// ---------------------------------------------------------------------------
__global__ __launch_bounds__(256) void ktv_mfma_kernel(
    const __hip_bfloat16* __restrict__ qkv, float* __restrict__ G)
{
    __shared__ __hip_bfloat16 kT[4][48][40];
    __shared__ __hip_bfloat16 vT[4][48][40];
    __shared__ float red[4][48][49];   // +1 pad: quad rows land on distinct banks

    const int bh = blockIdx.y; const int b = bh >> 3; const int h = bh & 7;
    const int lbase = blockIdx.x * 256;
    const int t = threadIdx.x;
    const int w = t >> 6, lane = t & 63;
    const int r16 = lane & 15, quad = lane >> 4;

    f32x4 acc[3][3];
    #pragma unroll
    for (int mi = 0; mi < 3; ++mi)
        #pragma unroll
        for (int ni = 0; ni < 3; ++ni)
            acc[mi][ni] = (f32x4){0.f, 0.f, 0.f, 0.f};

    const int mat  = t & 1;        // 0 = k, 1 = v
    const int lrow = t >> 1;       // 0..127
    const int tile = lrow >> 5, l_in = lrow & 31;
    const __hip_bfloat16* src = qkv + 384 + mat * 384 + h * 48;
    __hip_bfloat16* dstT = (mat ? &vT[0][0][0] : &kT[0][0][0]) + ((size_t)tile * 48 * 40 + l_in);

    for (int it = 0; it < 2; ++it) {
        const int l0 = lbase + it * 128;
        const __hip_bfloat16* p = src + (size_t)(b * 4096 + l0 + lrow) * 1152;
        __hip_bfloat16 row[48];
        #pragma unroll
        for (int j = 0; j < 6; ++j) {
            uint4 v = *(const uint4*)(p + j * 8);
            __builtin_memcpy(&row[j * 8], &v, 16);
        }
        #pragma unroll
        for (int d = 0; d < 48; ++d)
            dstT[d * 40] = row[d];
        __syncthreads();

        bf16x8 af[3], bfr[3];
        #pragma unroll
        for (int mi = 0; mi < 3; ++mi)
            af[mi] = *(const bf16x8*)&kT[w][mi * 16 + r16][quad * 8];
        #pragma unroll
        for (int ni = 0; ni < 3; ++ni)
            bfr[ni] = *(const bf16x8*)&vT[w][ni * 16 + r16][quad * 8];
        #pragma unroll
        for (int mi = 0; mi < 3; ++mi)
            #pragma unroll
            for (int ni = 0; ni < 3; ++ni)
                acc[mi][ni] = __builtin_amdgcn_mfma_f32_16x16x32_bf16(af[mi], bfr[ni], acc[mi][ni], 0, 0, 0);
        __syncthreads();
    }

    #pragma unroll
    for (int mi = 0; mi < 3; ++mi)
        #pragma unroll
        for (int ni = 0; ni < 3; ++ni)
            #pragma unroll
            for (int reg = 0; reg < 4; ++reg)
                red[w][mi * 16 + quad * 4 + reg][ni * 16 + r16] = acc[mi][ni][reg];
    __syncthreads();

    float* Gb = G + (size_t)bh * 2304;
    for (int cell = t; cell < 2304; cell += 256) {
        int row = cell / 48, col = cell % 48;
        float s = red[0][row][col] + red[1][row][col] + red[2][row][col] + red[3][row][col];
        atomicAdd(&Gb[cell], s);
    }
}

// ---------------------------------------------------------------------------
// attn = G * invnorm_k[d] * temp[h] -> fp32 out;  attn2 = attn * invnorm_q[d]
// invnorm computed inline from sumsq.
// ---------------------------------------------------------------------------
__global__ void scale_attn_kernel(
    const float* __restrict__ G, const float* __restrict__ sumsq,
    const float* __restrict__ temp,
    float* __restrict__ attn_out, float* __restrict__ attn2)
{
    int bh = blockIdx.x; int b = bh >> 3; int h = bh & 7;
    float tf = temp[h];
    int t = threadIdx.x;
    __shared__ float ink_s[48], inq_s[48];
    if (t < 48) {
        ink_s[t] = 1.f / fmaxf(sqrtf(sumsq[b * 768 + 384 + h * 48 + t]), 1e-12f);
        inq_s[t] = 1.f / fmaxf(sqrtf(sumsq[b * 768 +       h * 48 + t]), 1e-12f);
    }
    __syncthreads();
    for (int e = t; e < 2304; e += 256) {
        int dk = e / 48;
        float av  = G[(size_t)bh * 2304 + e] * ink_s[dk] * tf;
        attn_out[(size_t)bh * 2304 + e] = av;
        attn2[(size_t)bh * 2304 + e]    = av * inq_s[dk];
    }
}

// ---------------------------------------------------------------------------
// y[b,l,h*48+e] = sum_d q[b,h,l,d]*attn2[d,e] + lepe(v)  — MFMA version.
// ---------------------------------------------------------------------------
__global__ __launch_bounds__(256) void qattn_lepe_mfma(
    const __hip_bfloat16* __restrict__ qkv, const float* __restrict__ attn2,
    const float* __restrict__ conv_w, const float* __restrict__ conv_b,
    __hip_bfloat16* __restrict__ y)
{
    __shared__ __attribute__((aligned(16))) char smem[26624];
    __hip_bfloat16 (*qs)[72]  = (__hip_bfloat16 (*)[72])smem;            // [128][72]
    __hip_bfloat16 (*a2s)[72] = (__hip_bfloat16 (*)[72])(smem + 18432);  // [48][72]
    float (*ys)[52]           = (float (*)[52])smem;                     // [128][52]
    __shared__ __hip_bfloat16 vs[4][64][48];   // 24576 B
    __shared__ float cwT[9][48];
    __shared__ float cb[48];

    const int bh = blockIdx.y; const int b = bh >> 3; const int h = bh & 7;
    const int yi0 = blockIdx.x * 2;            // first image row of this block
    const int l0  = yi0 * 64;                  // first L index
    const int t = threadIdx.x;
    const int w = t >> 6, lane = t & 63;
    const int r16 = lane & 15, quad = lane >> 4;

    // ---- stage q tile (128 x 48, k-pad 48..63 = 0) ----
    const __hip_bfloat16* qbase = qkv + (size_t)(b * 4096 + l0) * 1152 + h * 48;
    #pragma unroll
    for (int i = 0; i < 3; ++i) {
        int chunk = t + i * 256;               // 768 chunks
        int row = chunk / 6, cg = chunk % 6;
        *(bf16x8*)&qs[row][cg * 8] = load8(qbase + (size_t)row * 1152 + cg * 8);
    }
    *(bf16x8*)&qs[t >> 1][48 + (t & 1) * 8] = (bf16x8)0;   // zero pad k 48..63

    // ---- stage attn2 transposed: a2s[e][d] (bf16, k-pad 48..63 = 0) ----
    const float* a2g = attn2 + (size_t)bh * 2304;
    for (int i = t; i < 3072; i += 256) {
        int e = i >> 6, dd = i & 63;
        float val = (dd < 48) ? a2g[dd * 48 + e] : 0.f;
        a2s[e][dd] = __float2bfloat16(val);
    }

    // ---- stage v image rows yi0-1 .. yi0+2 (zeros outside image) ----
    const __hip_bfloat16* vbase = qkv + (size_t)b * 4096 * 1152 + 768 + h * 48;
    #pragma unroll
    for (int i = 0; i < 6; ++i) {
        int chunk = t + i * 256;               // 1536 chunks
        int r = chunk / 384, rem = chunk % 384;
        int xx = rem / 6, cg = rem % 6;
        int yy = yi0 - 1 + r;
        bf16x8 v = (yy >= 0 && yy < 64)
            ? load8(vbase + (size_t)(yy * 64 + xx) * 1152 + cg * 8)
            : (bf16x8)0;
        *(bf16x8*)&vs[r][xx][cg * 8] = v;
    }

    // ---- conv weights (transposed) + bias ----
    for (int i = t; i < 432; i += 256)
        cwT[i / 48][i % 48] = conv_w[(h * 48 + (i % 48)) * 9 + (i / 48)];
    if (t < 48) cb[t] = conv_b[h * 48 + t];
    __syncthreads();

    // ---- MFMA: wave w computes rows w*32..w*32+31 ----
    f32x4 acc[2][3];
    #pragma unroll
    for (int mi = 0; mi < 2; ++mi)
        #pragma unroll
        for (int ni = 0; ni < 3; ++ni)
            acc[mi][ni] = (f32x4){0.f, 0.f, 0.f, 0.f};
    #pragma unroll
    for (int ks = 0; ks < 2; ++ks) {
        int kb = ks * 32 + quad * 8;
        bf16x8 af[2], bfr[3];
        #pragma unroll
        for (int mi = 0; mi < 2; ++mi)
            af[mi] = *(const bf16x8*)&qs[w * 32 + mi * 16 + r16][kb];
        #pragma unroll
        for (int ni = 0; ni < 3; ++ni)
            bfr[ni] = *(const bf16x8*)&a2s[ni * 16 + r16][kb];
        #pragma unroll
        for (int mi = 0; mi < 2; ++mi)
            #pragma unroll
            for (int ni = 0; ni < 3; ++ni)
                acc[mi][ni] = __builtin_amdgcn_mfma_f32_16x16x32_bf16(af[mi], bfr[ni], acc[mi][ni], 0, 0, 0);
    }
    __syncthreads();   // all waves done reading qs/a2s — safe to alias as ys

    // ---- write matmul result to ys (C/D layout: col=lane&15, row=quad*4+reg)
    #pragma unroll
    for (int mi = 0; mi < 2; ++mi)
        #pragma unroll
        for (int ni = 0; ni < 3; ++ni)
            #pragma unroll
            for (int reg = 0; reg < 4; ++reg)
                ys[w * 32 + mi * 16 + quad * 4 + reg][ni * 16 + r16] = acc[mi][ni][reg];
    __syncthreads();

    // ---- conv + bias + store (channel-vectorized, 8 ch per group) ----
    __hip_bfloat16* ybase = y + (size_t)(b * 4096 + l0) * 384 + h * 48;
    #pragma unroll
    for (int i = 0; i < 3; ++i) {
        int g = t + i * 256;                   // 768 groups
        int l_in = g / 6, cg = g % 6, e0 = cg * 8;
        int xi = l_in & 63, vr0 = l_in >> 6;   // local image col / base v-row
        float o[8];
        #pragma unroll
        for (int j = 0; j < 8; ++j) o[j] = ys[l_in][e0 + j] + cb[e0 + j];
        #pragma unroll
        for (int dy = 0; dy < 3; ++dy) {
            #pragma unroll
            for (int dx = 0; dx < 3; ++dx) {
                int xx = xi + dx - 1;
                if (xx < 0 || xx > 63) continue;
                bf16x8 vv = *(const bf16x8*)&vs[vr0 + dy][xx][e0];
                const float* cwp = &cwT[dy * 3 + dx][e0];
                #pragma unroll
                for (int j = 0; j < 8; ++j) o[j] += b2f(vv[j]) * cwp[j];
            }
        }
        __hip_bfloat16 ob[8];
        #pragma unroll
        for (int j = 0; j < 8; ++j) ob[j] = __float2bfloat16(o[j]);
        uint4 pk; __builtin_memcpy(&pk, ob, 16);
        *(uint4*)(ybase + (size_t)l_in * 384 + e0) = pk;
    }
}

// ---------------------------------------------------------------------------
extern "C" void kernel_launch(void* const* d_in, const int* in_sizes, int n_in,
                              void* d_out, int out_size, void* d_ws, size_t ws_size,
                              hipStream_t stream)
{
    const float* x      = (const float*)d_in[0];
    const float* qkv_w  = (const float*)d_in[1];
    const float* qkv_b  = (const float*)d_in[2];
    const float* proj_w = (const float*)d_in[3];
    const float* proj_b = (const float*)d_in[4];
    const float* temp   = (const float*)d_in[5];
    const float* conv_w = (const float*)d_in[6];
    const float* conv_b = (const float*)d_in[7];

    char* ws = (char*)d_ws;
    __hip_bfloat16* qkv = (__hip_bfloat16*)(ws);                 // 75,497,472 B
    __hip_bfloat16* yb  = (__hip_bfloat16*)(ws + 75497472);      // 25,165,824 B
    float* sumsq = (float*)(ws + 100663296);                     // 24,576 B
    float* G     = (float*)(ws + 100687872);                     // 589,824 B
    float* attn2 = (float*)(ws + 101302272);                     // 589,824 B
    __hip_bfloat16* qkv_wb  = (__hip_bfloat16*)(ws + 101892096); // 884,736 B
    __hip_bfloat16* proj_wb = (__hip_bfloat16*)(ws + 102776832); // 294,912 B

    float* out      = (float*)d_out;
    float* attn_out = out + 12582912;

    // zero the atomic accumulators (sumsq + G are contiguous)
    (void)hipMemsetAsync(ws + 100663296, 0, 614400, stream);

    // 0) convert qkv_w, proj_w to bf16 (weights only; x cvt fused into GEMM)
    cvt_kernel<<<288, 256, 0, stream>>>(qkv_w, qkv_wb, proj_w, proj_wb);
    // 1) qkv = x @ qkv_w^T + qkv_b  (fp32 A fused-convert -> bf16 out),
    //    fused q/k column sumsq.  128x64 tile: 256 row-tiles x 18 col-tiles.
    gemm_bf16_nt<float, __hip_bfloat16, 384, true><<<4608, 256, 0, stream>>>(
        x, qkv_wb, qkv_b, qkv, 1152, 18, sumsq);
    // 2) G = k^T v  (MFMA)
    ktv_mfma_kernel<<<dim3(16, 64), 256, 0, stream>>>(qkv, G);
    // 3) attn (fp32 out) + attn2 (fp32, q-norm folded); invnorm fused inline
    scale_attn_kernel<<<64, 256, 0, stream>>>(G, sumsq, temp, attn_out, attn2);
    // 4) y = q @ attn2 + lepe   (MFMA, bf16 out)
    qattn_lepe_mfma<<<dim3(32, 64), 256, 0, stream>>>(qkv, attn2, conv_w, conv_b, yb);
    // 5) out = y @ proj_w^T + proj_b   (bf16 -> fp32)
    gemm_bf16_nt<__hip_bfloat16, float, 384, false><<<1536, 256, 0, stream>>>(
        yb, proj_wb, proj_b, out, 384, 6, nullptr);
}

// Round 3
// 222.797 us; speedup vs baseline: 1.1013x; 1.1013x over previous
//
#include <hip/hip_runtime.h>
#include <hip/hip_bf16.h>

// B=8, L=4096, C=384, h=8, d=48, H=W=64
// Inputs/outputs fp32 (per reference). Internals: x/weights pre-converted to
// bf16 (ws), qkv/y bf16 (ws), sumsq/G/attn2 fp32 (ws).

typedef __bf16 bf16x8 __attribute__((ext_vector_type(8)));
typedef float f32x4 __attribute__((ext_vector_type(4)));

__device__ inline __bf16 f2b(float f) {
    __hip_bfloat16 h = __float2bfloat16(f);
    __bf16 r; __builtin_memcpy(&r, &h, 2); return r;
}
__device__ inline float b2f(__hip_bfloat16 h) { return __bfloat162float(h); }
__device__ inline float b2f(__bf16 v) {
    __hip_bfloat16 h; __builtin_memcpy(&h, &v, 2); return __bfloat162float(h);
}

__device__ inline bf16x8 load8(const __hip_bfloat16* p) {
    uint4 v = *(const uint4*)p;
    bf16x8 r; __builtin_memcpy(&r, &v, 16); return r;
}
__device__ inline bf16x8 load8(const float* p) {
    float4 a = *(const float4*)p;
    float4 b = *(const float4*)(p + 4);
    bf16x8 r;
    r[0] = f2b(a.x); r[1] = f2b(a.y); r[2] = f2b(a.z); r[3] = f2b(a.w);
    r[4] = f2b(b.x); r[5] = f2b(b.y); r[6] = f2b(b.z); r[7] = f2b(b.w);
    return r;
}

__device__ inline void storef(float* p, float v) { *p = v; }
__device__ inline void storef(__hip_bfloat16* p, float v) { *p = __float2bfloat16(v); }

// async 16B global -> LDS (wave-uniform base + lane*16 dest required)
__device__ inline void gl_lds16(const __hip_bfloat16* g, __hip_bfloat16* l) {
    __builtin_amdgcn_global_load_lds(
        (const __attribute__((address_space(1))) void*)g,
        (__attribute__((address_space(3))) void*)l,
        16, 0, 0);
}

// ---------------------------------------------------------------------------
// fp32 -> bf16 conversion: x (6144 blocks), qkv_w (216), proj_w (72)
// ---------------------------------------------------------------------------
__global__ __launch_bounds__(256) void cvt_kernel(
    const float* __restrict__ x,  __hip_bfloat16* __restrict__ xb,
    const float* __restrict__ qw, __hip_bfloat16* __restrict__ qwb,
    const float* __restrict__ pw, __hip_bfloat16* __restrict__ pwb)
{
    int blk = blockIdx.x;
    const float* src; __hip_bfloat16* dst; int base;
    if (blk < 6144)      { src = x;  dst = xb;  base = blk; }
    else if (blk < 6360) { src = qw; dst = qwb; base = blk - 6144; }
    else                 { src = pw; dst = pwb; base = blk - 6360; }
    int i = base * 256 + threadIdx.x;
    bf16x8 v = load8(src + (size_t)i * 8);
    *(bf16x8*)(dst + (size_t)i * 8) = v;
}

// ---------------------------------------------------------------------------
// GEMM: C[M,N] = A[M,K] @ Bw[N,K]^T + bias[N], bf16 in, fp32 accum.
// Block tile 128x64, BK=64, 6 k-iters (K=384). 4 waves, each 64x32
// (4x2 MFMA 16x16x32, 32 AGPR acc). LDS double-buffered (48 KB -> 3 blk/CU,
// matching measured occupancy): per k-iter, ds_read frags of buf[cur], THEN
// issue next tile's global_load_lds into buf[cur^1], then MFMA; the single
// __syncthreads() per iter drains vmcnt AFTER compute, so the prefetch
// latency hides under the MFMAs (minimum-2-phase pipeline).
// Staging via global_load_lds width-16 (dest lane-contiguous as required);
// the GLOBAL source chunk is XOR-swizzled (chunk ^ (row&7)) so the logical
// LDS layout is bank-conflict-free on ds_read_b128 fragment reads.
// 1-D grid, XCD swizzle: all NXT col-tiles of one row-tile on one XCD.
// Optional fused column sum-of-squares (cols < 768) into sq via atomics.
// ---------------------------------------------------------------------------
template <typename TO, int KC, bool FUSE_SQ>
__global__ __launch_bounds__(256) void gemm_bf16_nt(
    const __hip_bfloat16* __restrict__ A,
    const __hip_bfloat16* __restrict__ Bw,
    const float* __restrict__ bias,
    TO* __restrict__ C,
    int N, int NXT,
    float* __restrict__ sq)
{
    __shared__ __hip_bfloat16 As[2][128 * 64];   // 2 x 16 KB
    __shared__ __hip_bfloat16 Bs[2][64 * 64];    // 2 x  8 KB
    const int t = threadIdx.x;
    const int w = t >> 6, lane = t & 63;
    const int r16 = lane & 15, quad = lane >> 4;
    const int bx  = blockIdx.x;
    const int xcd = bx & 7, seq = bx >> 3;
    const int n_t = seq % NXT, m_t = seq / NXT;
    const int m0 = (xcd + 8 * m_t) * 128;
    const int n0 = n_t * 64;
    const int wm = w >> 1, wn = w & 1;

    f32x4 acc[4][2];
    #pragma unroll
    for (int mi = 0; mi < 4; ++mi)
        #pragma unroll
        for (int ni = 0; ni < 2; ++ni)
            acc[mi][ni] = (f32x4){0.f, 0.f, 0.f, 0.f};

    // stage one 128x64 A-tile + 64x64 B-tile into buffer `buf`
    auto stage = [&](int buf, int k0) {
        // A: wave w stages rows [w*32, w*32+32), 8 chunks(16B)/row, 4/lane.
        // LDS dest chunk P = w*256 + p*64 + lane (contiguous); global source
        // column-chunk = (P&7) ^ (row&7)  [XOR swizzle].
        #pragma unroll
        for (int p = 0; p < 4; ++p) {
            int c = p * 64 + lane;                    // 0..255
            int rl = c >> 3;                          // row within wave's 32
            int cc = (c & 7) ^ (rl & 7);              // swizzled col chunk
            gl_lds16(A + (size_t)(m0 + w * 32 + rl) * KC + k0 + cc * 8,
                     &As[buf][(w * 256 + c) * 8]);
        }
        // B: wave w stages rows [w*16, w*16+16), 2/lane.
        #pragma unroll
        for (int p = 0; p < 2; ++p) {
            int c = p * 64 + lane;                    // 0..127
            int rl = c >> 3;                          // row within wave's 16
            int cc = (c & 7) ^ (rl & 7);
            gl_lds16(Bw + (size_t)(n0 + w * 16 + rl) * KC + k0 + cc * 8,
                     &Bs[buf][(w * 128 + c) * 8]);
        }
    };

    constexpr int NT = KC / 64;
    stage(0, 0);
    __syncthreads();   // drain prologue vmcnt

    #pragma unroll
    for (int ti = 0; ti < NT; ++ti) {
        const int cur = ti & 1;
        // 1) ds_read current tile's fragments (reads buf[cur] only)
        bf16x8 af[4][2], bfr[2][2];
        #pragma unroll
        for (int ks = 0; ks < 2; ++ks) {
            #pragma unroll
            for (int mi = 0; mi < 4; ++mi) {
                int row = wm * 64 + mi * 16 + r16;
                int pc  = (ks * 4 + quad) ^ (r16 & 7);   // physical chunk
                af[mi][ks] = *(const bf16x8*)&As[cur][row * 64 + pc * 8];
            }
            #pragma unroll
            for (int ni = 0; ni < 2; ++ni) {
                int row = wn * 32 + ni * 16 + r16;
                int pc  = (ks * 4 + quad) ^ (r16 & 7);
                bfr[ni][ks] = *(const bf16x8*)&Bs[cur][row * 64 + pc * 8];
            }
        }
        // 2) issue next tile's async loads into buf[cur^1] (no wait here;
        //    they fly during the MFMAs below, drained by the barrier)
        if (ti + 1 < NT) stage(cur ^ 1, (ti + 1) * 64);
        // 3) compute
        #pragma unroll
        for (int ks = 0; ks < 2; ++ks)
            #pragma unroll
            for (int mi = 0; mi < 4; ++mi)
                #pragma unroll
                for (int ni = 0; ni < 2; ++ni)
                    acc[mi][ni] = __builtin_amdgcn_mfma_f32_16x16x32_bf16(
                        af[mi][ks], bfr[ni][ks], acc[mi][ni], 0, 0, 0);
        // 4) single barrier per iter: drains vmcnt (prefetch landed) and
        //    retires all waves' ds_reads of buf[cur]
        __syncthreads();
    }

    #pragma unroll
    for (int ni = 0; ni < 2; ++ni) {
        int col = n0 + wn * 32 + ni * 16 + r16;
        float bv = bias[col];
        float s = 0.f;
        #pragma unroll
        for (int mi = 0; mi < 4; ++mi) {
            #pragma unroll
            for (int reg = 0; reg < 4; ++reg) {
                int row = m0 + wm * 64 + mi * 16 + quad * 4 + reg;
                float o = acc[mi][ni][reg] + bv;
                storef(&C[(size_t)row * N + col], o);
                s += o * o;
            }
        }
        if constexpr (FUSE_SQ) {
            if (col < 768) {
                s += __shfl_xor(s, 16);
                s += __shfl_xor(s, 32);
                if (quad == 0) {
                    int b = m0 >> 12;   // 4096 rows per batch
                    atomicAdd(&sq[b * 768 + col], s);
                }
            }
        }
    }
}

// ---------------------------------------------------------------------------
// G[bh] = k^T v  via MFMA.  Grid (16, 64): each block covers 256 of L for one
// (b,h) -> 1024 blocks (~4/CU for latency hiding). 4 waves on disjoint 32-l
// chunks; k,v tiles staged TRANSPOSED in LDS.
// ---------------------------------------------------------------------------
__global__ __launch_bounds__(256) void ktv_mfma_kernel(
    const __hip_bfloat16* __restrict__ qkv, float* __restrict__ G)
{
    __shared__ __hip_bfloat16 kT[4][48][40];
    __shared__ __hip_bfloat16 vT[4][48][40];
    __shared__ float red[4][48][49];   // +1 pad: quad rows land on distinct banks

    const int bh = blockIdx.y; const int b = bh >> 3; const int h = bh & 7;
    const int lbase = blockIdx.x * 256;
    const int t = threadIdx.x;
    const int w = t >> 6, lane = t & 63;
    const int r16 = lane & 15, quad = lane >> 4;

    f32x4 acc[3][3];
    #pragma unroll
    for (int mi = 0; mi < 3; ++mi)
        #pragma unroll
        for (int ni = 0; ni < 3; ++ni)
            acc[mi][ni] = (f32x4){0.f, 0.f, 0.f, 0.f};

    const int mat  = t & 1;        // 0 = k, 1 = v
    const int lrow = t >> 1;       // 0..127
    const int tile = lrow >> 5, l_in = lrow & 31;
    const __hip_bfloat16* src = qkv + 384 + mat * 384 + h * 48;
    __hip_bfloat16* dstT = (mat ? &vT[0][0][0] : &kT[0][0][0]) + ((size_t)tile * 48 * 40 + l_in);

    for (int it = 0; it < 2; ++it) {
        const int l0 = lbase + it * 128;
        const __hip_bfloat16* p = src + (size_t)(b * 4096 + l0 + lrow) * 1152;
        __hip_bfloat16 row[48];
        #pragma unroll
        for (int j = 0; j < 6; ++j) {
            uint4 v = *(const uint4*)(p + j * 8);
            __builtin_memcpy(&row[j * 8], &v, 16);
        }
        #pragma unroll
        for (int d = 0; d < 48; ++d)
            dstT[d * 40] = row[d];
        __syncthreads();

        bf16x8 af[3], bfr[3];
        #pragma unroll
        for (int mi = 0; mi < 3; ++mi)
            af[mi] = *(const bf16x8*)&kT[w][mi * 16 + r16][quad * 8];
        #pragma unroll
        for (int ni = 0; ni < 3; ++ni)
            bfr[ni] = *(const bf16x8*)&vT[w][ni * 16 + r16][quad * 8];
        #pragma unroll
        for (int mi = 0; mi < 3; ++mi)
            #pragma unroll
            for (int ni = 0; ni < 3; ++ni)
                acc[mi][ni] = __builtin_amdgcn_mfma_f32_16x16x32_bf16(af[mi], bfr[ni], acc[mi][ni], 0, 0, 0);
        __syncthreads();
    }

    #pragma unroll
    for (int mi = 0; mi < 3; ++mi)
        #pragma unroll
        for (int ni = 0; ni < 3; ++ni)
            #pragma unroll
            for (int reg = 0; reg < 4; ++reg)
                red[w][mi * 16 + quad * 4 + reg][ni * 16 + r16] = acc[mi][ni][reg];
    __syncthreads();

    float* Gb = G + (size_t)bh * 2304;
    for (int cell = t; cell < 2304; cell += 256) {
        int row = cell / 48, col = cell % 48;
        float s = red[0][row][col] + red[1][row][col] + red[2][row][col] + red[3][row][col];
        atomicAdd(&Gb[cell], s);
    }
}

// ---------------------------------------------------------------------------
// attn = G * invnorm_k[d] * temp[h] -> fp32 out;  attn2 = attn * invnorm_q[d]
// invnorm computed inline from sumsq.
// ---------------------------------------------------------------------------
__global__ void scale_attn_kernel(
    const float* __restrict__ G, const float* __restrict__ sumsq,
    const float* __restrict__ temp,
    float* __restrict__ attn_out, float* __restrict__ attn2)
{
    int bh = blockIdx.x; int b = bh >> 3; int h = bh & 7;
    float tf = temp[h];
    int t = threadIdx.x;
    __shared__ float ink_s[48], inq_s[48];
    if (t < 48) {
        ink_s[t] = 1.f / fmaxf(sqrtf(sumsq[b * 768 + 384 + h * 48 + t]), 1e-12f);
        inq_s[t] = 1.f / fmaxf(sqrtf(sumsq[b * 768 +       h * 48 + t]), 1e-12f);
    }
    __syncthreads();
    for (int e = t; e < 2304; e += 256) {
        int dk = e / 48;
        float av  = G[(size_t)bh * 2304 + e] * ink_s[dk] * tf;
        attn_out[(size_t)bh * 2304 + e] = av;
        attn2[(size_t)bh * 2304 + e]    = av * inq_s[dk];
    }
}

// ---------------------------------------------------------------------------
// y[b,l,h*48+e] = sum_d q[b,h,l,d]*attn2[d,e] + lepe(v)  — MFMA version.
// ---------------------------------------------------------------------------
__global__ __launch_bounds__(256) void qattn_lepe_mfma(
    const __hip_bfloat16* __restrict__ qkv, const float* __restrict__ attn2,
    const float* __restrict__ conv_w, const float* __restrict__ conv_b,
    __hip_bfloat16* __restrict__ y)
{
    __shared__ __attribute__((aligned(16))) char smem[26624];
    __hip_bfloat16 (*qs)[72]  = (__hip_bfloat16 (*)[72])smem;            // [128][72]
    __hip_bfloat16 (*a2s)[72] = (__hip_bfloat16 (*)[72])(smem + 18432);  // [48][72]
    float (*ys)[52]           = (float (*)[52])smem;                     // [128][52]
    __shared__ __hip_bfloat16 vs[4][64][48];   // 24576 B
    __shared__ float cwT[9][48];
    __shared__ float cb[48];

    const int bh = blockIdx.y; const int b = bh >> 3; const int h = bh & 7;
    const int yi0 = blockIdx.x * 2;            // first image row of this block
    const int l0  = yi0 * 64;                  // first L index
    const int t = threadIdx.x;
    const int w = t >> 6, lane = t & 63;
    const int r16 = lane & 15, quad = lane >> 4;

    // ---- stage q tile (128 x 48, k-pad 48..63 = 0) ----
    const __hip_bfloat16* qbase = qkv + (size_t)(b * 4096 + l0) * 1152 + h * 48;
    #pragma unroll
    for (int i = 0; i < 3; ++i) {
        int chunk = t + i * 256;               // 768 chunks
        int row = chunk / 6, cg = chunk % 6;
        *(bf16x8*)&qs[row][cg * 8] = load8(qbase + (size_t)row * 1152 + cg * 8);
    }
    *(bf16x8*)&qs[t >> 1][48 + (t & 1) * 8] = (bf16x8)0;   // zero pad k 48..63

    // ---- stage attn2 transposed: a2s[e][d] (bf16, k-pad 48..63 = 0) ----
    const float* a2g = attn2 + (size_t)bh * 2304;
    for (int i = t; i < 3072; i += 256) {
        int e = i >> 6, dd = i & 63;
        float val = (dd < 48) ? a2g[dd * 48 + e] : 0.f;
        a2s[e][dd] = __float2bfloat16(val);
    }

    // ---- stage v image rows yi0-1 .. yi0+2 (zeros outside image) ----
    const __hip_bfloat16* vbase = qkv + (size_t)b * 4096 * 1152 + 768 + h * 48;
    #pragma unroll
    for (int i = 0; i < 6; ++i) {
        int chunk = t + i * 256;               // 1536 chunks
        int r = chunk / 384, rem = chunk % 384;
        int xx = rem / 6, cg = rem % 6;
        int yy = yi0 - 1 + r;
        bf16x8 v = (yy >= 0 && yy < 64)
            ? load8(vbase + (size_t)(yy * 64 + xx) * 1152 + cg * 8)
            : (bf16x8)0;
        *(bf16x8*)&vs[r][xx][cg * 8] = v;
    }

    // ---- conv weights (transposed) + bias ----
    for (int i = t; i < 432; i += 256)
        cwT[i / 48][i % 48] = conv_w[(h * 48 + (i % 48)) * 9 + (i / 48)];
    if (t < 48) cb[t] = conv_b[h * 48 + t];
    __syncthreads();

    // ---- MFMA: wave w computes rows w*32..w*32+31 ----
    f32x4 acc[2][3];
    #pragma unroll
    for (int mi = 0; mi < 2; ++mi)
        #pragma unroll
        for (int ni = 0; ni < 3; ++ni)
            acc[mi][ni] = (f32x4){0.f, 0.f, 0.f, 0.f};
    #pragma unroll
    for (int ks = 0; ks < 2; ++ks) {
        int kb = ks * 32 + quad * 8;
        bf16x8 af[2], bfr[3];
        #pragma unroll
        for (int mi = 0; mi < 2; ++mi)
            af[mi] = *(const bf16x8*)&qs[w * 32 + mi * 16 + r16][kb];
        #pragma unroll
        for (int ni = 0; ni < 3; ++ni)
            bfr[ni] = *(const bf16x8*)&a2s[ni * 16 + r16][kb];
        #pragma unroll
        for (int mi = 0; mi < 2; ++mi)
            #pragma unroll
            for (int ni = 0; ni < 3; ++ni)
                acc[mi][ni] = __builtin_amdgcn_mfma_f32_16x16x32_bf16(af[mi], bfr[ni], acc[mi][ni], 0, 0, 0);
    }
    __syncthreads();   // all waves done reading qs/a2s — safe to alias as ys

    // ---- write matmul result to ys (C/D layout: col=lane&15, row=quad*4+reg)
    #pragma unroll
    for (int mi = 0; mi < 2; ++mi)
        #pragma unroll
        for (int ni = 0; ni < 3; ++ni)
            #pragma unroll
            for (int reg = 0; reg < 4; ++reg)
                ys[w * 32 + mi * 16 + quad * 4 + reg][ni * 16 + r16] = acc[mi][ni][reg];
    __syncthreads();

    // ---- conv + bias + store (channel-vectorized, 8 ch per group) ----
    __hip_bfloat16* ybase = y + (size_t)(b * 4096 + l0) * 384 + h * 48;
    #pragma unroll
    for (int i = 0; i < 3; ++i) {
        int g = t + i * 256;                   // 768 groups
        int l_in = g / 6, cg = g % 6, e0 = cg * 8;
        int xi = l_in & 63, vr0 = l_in >> 6;   // local image col / base v-row
        float o[8];
        #pragma unroll
        for (int j = 0; j < 8; ++j) o[j] = ys[l_in][e0 + j] + cb[e0 + j];
        #pragma unroll
        for (int dy = 0; dy < 3; ++dy) {
            #pragma unroll
            for (int dx = 0; dx < 3; ++dx) {
                int xx = xi + dx - 1;
                if (xx < 0 || xx > 63) continue;
                bf16x8 vv = *(const bf16x8*)&vs[vr0 + dy][xx][e0];
                const float* cwp = &cwT[dy * 3 + dx][e0];
                #pragma unroll
                for (int j = 0; j < 8; ++j) o[j] += b2f(vv[j]) * cwp[j];
            }
        }
        __hip_bfloat16 ob[8];
        #pragma unroll
        for (int j = 0; j < 8; ++j) ob[j] = __float2bfloat16(o[j]);
        uint4 pk; __builtin_memcpy(&pk, ob, 16);
        *(uint4*)(ybase + (size_t)l_in * 384 + e0) = pk;
    }
}

// ---------------------------------------------------------------------------
extern "C" void kernel_launch(void* const* d_in, const int* in_sizes, int n_in,
                              void* d_out, int out_size, void* d_ws, size_t ws_size,
                              hipStream_t stream)
{
    const float* x      = (const float*)d_in[0];
    const float* qkv_w  = (const float*)d_in[1];
    const float* qkv_b  = (const float*)d_in[2];
    const float* proj_w = (const float*)d_in[3];
    const float* proj_b = (const float*)d_in[4];
    const float* temp   = (const float*)d_in[5];
    const float* conv_w = (const float*)d_in[6];
    const float* conv_b = (const float*)d_in[7];

    char* ws = (char*)d_ws;
    __hip_bfloat16* qkv = (__hip_bfloat16*)(ws);                 // 75,497,472 B
    __hip_bfloat16* yb  = (__hip_bfloat16*)(ws + 75497472);      // 25,165,824 B
    float* sumsq = (float*)(ws + 100663296);                     // 24,576 B
    float* G     = (float*)(ws + 100687872);                     // 589,824 B
    float* attn2 = (float*)(ws + 101302272);                     // 589,824 B
    // x_bf16 aliases yb (dead until qattn_lepe); weight bf16 copies appended
    __hip_bfloat16* x_bf16  = yb;
    __hip_bfloat16* qkv_wb  = (__hip_bfloat16*)(ws + 101892096); // 884,736 B
    __hip_bfloat16* proj_wb = (__hip_bfloat16*)(ws + 102776832); // 294,912 B

    float* out      = (float*)d_out;
    float* attn_out = out + 12582912;

    // zero the atomic accumulators (sumsq + G are contiguous)
    (void)hipMemsetAsync(ws + 100663296, 0, 614400, stream);

    // 0) convert x, qkv_w, proj_w to bf16
    cvt_kernel<<<6432, 256, 0, stream>>>(x, x_bf16, qkv_w, qkv_wb, proj_w, proj_wb);
    // 1) qkv = x @ qkv_w^T + qkv_b  (bf16 -> bf16), fused q/k column sumsq
    gemm_bf16_nt<__hip_bfloat16, 384, true><<<4608, 256, 0, stream>>>(
        x_bf16, qkv_wb, qkv_b, qkv, 1152, 18, sumsq);
    // 2) G = k^T v  (MFMA)
    ktv_mfma_kernel<<<dim3(16, 64), 256, 0, stream>>>(qkv, G);
    // 3) attn (fp32 out) + attn2 (fp32, q-norm folded); invnorm fused inline
    scale_attn_kernel<<<64, 256, 0, stream>>>(G, sumsq, temp, attn_out, attn2);
    // 4) y = q @ attn2 + lepe   (MFMA, bf16 out — overwrites x_bf16 alias)
    qattn_lepe_mfma<<<dim3(32, 64), 256, 0, stream>>>(qkv, attn2, conv_w, conv_b, yb);
    // 5) out = y @ proj_w^T + proj_b   (bf16 -> fp32)
    gemm_bf16_nt<float, 384, false><<<1536, 256, 0, stream>>>(
        yb, proj_wb, proj_b, out, 384, 6, nullptr);
}

// Round 4
// 219.260 us; speedup vs baseline: 1.1191x; 1.0161x over previous
//
#include <hip/hip_runtime.h>
#include <hip/hip_bf16.h>

// B=8, L=4096, C=384, h=8, d=48, H=W=64
// Inputs/outputs fp32 (per reference). Internals: x/weights pre-converted to
// bf16 (ws), qkv/y bf16 (ws), sumsq/G fp32 (ws). attn2 never materialized:
// scale_attn is fused into qattn_lepe (computed per-block from G+sumsq).

typedef __bf16 bf16x8 __attribute__((ext_vector_type(8)));
typedef float f32x4 __attribute__((ext_vector_type(4)));

__device__ inline __bf16 f2b(float f) {
    __hip_bfloat16 h = __float2bfloat16(f);
    __bf16 r; __builtin_memcpy(&r, &h, 2); return r;
}
__device__ inline float b2f(__hip_bfloat16 h) { return __bfloat162float(h); }
__device__ inline float b2f(__bf16 v) {
    __hip_bfloat16 h; __builtin_memcpy(&h, &v, 2); return __bfloat162float(h);
}

__device__ inline bf16x8 load8(const __hip_bfloat16* p) {
    uint4 v = *(const uint4*)p;
    bf16x8 r; __builtin_memcpy(&r, &v, 16); return r;
}
__device__ inline bf16x8 load8(const float* p) {
    float4 a = *(const float4*)p;
    float4 b = *(const float4*)(p + 4);
    bf16x8 r;
    r[0] = f2b(a.x); r[1] = f2b(a.y); r[2] = f2b(a.z); r[3] = f2b(a.w);
    r[4] = f2b(b.x); r[5] = f2b(b.y); r[6] = f2b(b.z); r[7] = f2b(b.w);
    return r;
}

__device__ inline void storef(float* p, float v) { *p = v; }
__device__ inline void storef(__hip_bfloat16* p, float v) { *p = __float2bfloat16(v); }

// async 16B global -> LDS (wave-uniform base + lane*16 dest required)
__device__ inline void gl_lds16(const __hip_bfloat16* g, __hip_bfloat16* l) {
    __builtin_amdgcn_global_load_lds(
        (const __attribute__((address_space(1))) void*)g,
        (__attribute__((address_space(3))) void*)l,
        16, 0, 0);
}

// ---------------------------------------------------------------------------
// fp32 -> bf16 conversion: x (6144 blocks), qkv_w (216), proj_w (72).
// Blocks >= 6432 zero the sumsq+G accumulator region (replaces memset).
// ---------------------------------------------------------------------------
__global__ __launch_bounds__(256) void cvt_kernel(
    const float* __restrict__ x,  __hip_bfloat16* __restrict__ xb,
    const float* __restrict__ qw, __hip_bfloat16* __restrict__ qwb,
    const float* __restrict__ pw, __hip_bfloat16* __restrict__ pwb,
    uint4* __restrict__ zdst)
{
    int blk = blockIdx.x;
    if (blk >= 6432) {   // 150 blocks: zero 614400 B (sumsq + G)
        zdst[(size_t)(blk - 6432) * 256 + threadIdx.x] = (uint4){0, 0, 0, 0};
        return;
    }
    const float* src; __hip_bfloat16* dst; int base;
    if (blk < 6144)      { src = x;  dst = xb;  base = blk; }
    else if (blk < 6360) { src = qw; dst = qwb; base = blk - 6144; }
    else                 { src = pw; dst = pwb; base = blk - 6360; }
    int i = base * 256 + threadIdx.x;
    bf16x8 v = load8(src + (size_t)i * 8);
    *(bf16x8*)(dst + (size_t)i * 8) = v;
}

// ---------------------------------------------------------------------------
// GEMM: C[M,N] = A[M,K] @ Bw[N,K]^T + bias[N], bf16 in, fp32 accum.
// Block tile 128x64, BK=64, 6 k-iters (K=384). 4 waves, each 64x32
// (4x2 MFMA 16x16x32, 32 AGPR acc). Single-buffered LDS (24 KB -> high
// residency; measured best vs 128x128 tile and vs double-buffer on thin K).
// Staging via global_load_lds width-16 (dest lane-contiguous as required);
// the GLOBAL source chunk is XOR-swizzled (chunk ^ (row&7)) so the logical
// LDS layout is bank-conflict-free on ds_read_b128 fragment reads.
// 1-D grid, XCD swizzle: all NXT col-tiles of one row-tile on one XCD.
// Optional fused column sum-of-squares (cols < 768) into sq via atomics.
// ---------------------------------------------------------------------------
template <typename TO, int KC, bool FUSE_SQ>
__global__ __launch_bounds__(256) void gemm_bf16_nt(
    const __hip_bfloat16* __restrict__ A,
    const __hip_bfloat16* __restrict__ Bw,
    const float* __restrict__ bias,
    TO* __restrict__ C,
    int N, int NXT,
    float* __restrict__ sq)
{
    __shared__ __hip_bfloat16 As[128 * 64];   // 16 KB
    __shared__ __hip_bfloat16 Bs[64 * 64];    //  8 KB
    const int t = threadIdx.x;
    const int w = t >> 6, lane = t & 63;
    const int r16 = lane & 15, quad = lane >> 4;
    const int bx  = blockIdx.x;
    const int xcd = bx & 7, seq = bx >> 3;
    const int n_t = seq % NXT, m_t = seq / NXT;
    const int m0 = (xcd + 8 * m_t) * 128;
    const int n0 = n_t * 64;
    const int wm = w >> 1, wn = w & 1;

    f32x4 acc[4][2];
    #pragma unroll
    for (int mi = 0; mi < 4; ++mi)
        #pragma unroll
        for (int ni = 0; ni < 2; ++ni)
            acc[mi][ni] = (f32x4){0.f, 0.f, 0.f, 0.f};

    for (int k0 = 0; k0 < KC; k0 += 64) {
        // A: wave w stages rows [w*32, w*32+32), 8 chunks(16B)/row, 4/lane.
        // LDS dest chunk P = w*256 + p*64 + lane (contiguous); global source
        // column-chunk = (P&7) ^ (row&7)  [XOR swizzle].
        #pragma unroll
        for (int p = 0; p < 4; ++p) {
            int c = p * 64 + lane;                    // 0..255
            int rl = c >> 3;                          // row within wave's 32
            int cc = (c & 7) ^ (rl & 7);              // swizzled col chunk
            gl_lds16(A + (size_t)(m0 + w * 32 + rl) * KC + k0 + cc * 8,
                     &As[(w * 256 + c) * 8]);
        }
        // B: wave w stages rows [w*16, w*16+16), 2/lane.
        #pragma unroll
        for (int p = 0; p < 2; ++p) {
            int c = p * 64 + lane;                    // 0..127
            int rl = c >> 3;                          // row within wave's 16
            int cc = (c & 7) ^ (rl & 7);
            gl_lds16(Bw + (size_t)(n0 + w * 16 + rl) * KC + k0 + cc * 8,
                     &Bs[(w * 128 + c) * 8]);
        }
        __syncthreads();   // drains vmcnt (incl. global_load_lds)
        bf16x8 af[4][2], bfr[2][2];
        #pragma unroll
        for (int ks = 0; ks < 2; ++ks) {
            #pragma unroll
            for (int mi = 0; mi < 4; ++mi) {
                int row = wm * 64 + mi * 16 + r16;
                int pc  = (ks * 4 + quad) ^ (r16 & 7);   // physical chunk
                af[mi][ks] = *(const bf16x8*)&As[row * 64 + pc * 8];
            }
            #pragma unroll
            for (int ni = 0; ni < 2; ++ni) {
                int row = wn * 32 + ni * 16 + r16;
                int pc  = (ks * 4 + quad) ^ (r16 & 7);
                bfr[ni][ks] = *(const bf16x8*)&Bs[row * 64 + pc * 8];
            }
        }
        #pragma unroll
        for (int ks = 0; ks < 2; ++ks)
            #pragma unroll
            for (int mi = 0; mi < 4; ++mi)
                #pragma unroll
                for (int ni = 0; ni < 2; ++ni)
                    acc[mi][ni] = __builtin_amdgcn_mfma_f32_16x16x32_bf16(
                        af[mi][ks], bfr[ni][ks], acc[mi][ni], 0, 0, 0);
        __syncthreads();
    }

    #pragma unroll
    for (int ni = 0; ni < 2; ++ni) {
        int col = n0 + wn * 32 + ni * 16 + r16;
        float bv = bias[col];
        float s = 0.f;
        #pragma unroll
        for (int mi = 0; mi < 4; ++mi) {
            #pragma unroll
            for (int reg = 0; reg < 4; ++reg) {
                int row = m0 + wm * 64 + mi * 16 + quad * 4 + reg;
                float o = acc[mi][ni][reg] + bv;
                storef(&C[(size_t)row * N + col], o);
                s += o * o;
            }
        }
        if constexpr (FUSE_SQ) {
            if (col < 768) {
                s += __shfl_xor(s, 16);
                s += __shfl_xor(s, 32);
                if (quad == 0) {
                    int b = m0 >> 12;   // 4096 rows per batch
                    atomicAdd(&sq[b * 768 + col], s);
                }
            }
        }
    }
}

// ---------------------------------------------------------------------------
// G[bh] = k^T v  via MFMA.  Grid (16, 64): each block covers 256 of L for one
// (b,h) -> 1024 blocks (~4/CU for latency hiding). 4 waves on disjoint 32-l
// chunks; k,v tiles staged TRANSPOSED in LDS.
// ---------------------------------------------------------------------------
__global__ __launch_bounds__(256) void ktv_mfma_kernel(
    const __hip_bfloat16* __restrict__ qkv, float* __restrict__ G)
{
    __shared__ __hip_bfloat16 kT[4][48][40];
    __shared__ __hip_bfloat16 vT[4][48][40];
    __shared__ float red[4][48][49];   // +1 pad: quad rows land on distinct banks

    const int bh = blockIdx.y; const int b = bh >> 3; const int h = bh & 7;
    const int lbase = blockIdx.x * 256;
    const int t = threadIdx.x;
    const int w = t >> 6, lane = t & 63;
    const int r16 = lane & 15, quad = lane >> 4;

    f32x4 acc[3][3];
    #pragma unroll
    for (int mi = 0; mi < 3; ++mi)
        #pragma unroll
        for (int ni = 0; ni < 3; ++ni)
            acc[mi][ni] = (f32x4){0.f, 0.f, 0.f, 0.f};

    const int mat  = t & 1;        // 0 = k, 1 = v
    const int lrow = t >> 1;       // 0..127
    const int tile = lrow >> 5, l_in = lrow & 31;
    const __hip_bfloat16* src = qkv + 384 + mat * 384 + h * 48;
    __hip_bfloat16* dstT = (mat ? &vT[0][0][0] : &kT[0][0][0]) + ((size_t)tile * 48 * 40 + l_in);

    for (int it = 0; it < 2; ++it) {
        const int l0 = lbase + it * 128;
        const __hip_bfloat16* p = src + (size_t)(b * 4096 + l0 + lrow) * 1152;
        __hip_bfloat16 row[48];
        #pragma unroll
        for (int j = 0; j < 6; ++j) {
            uint4 v = *(const uint4*)(p + j * 8);
            __builtin_memcpy(&row[j * 8], &v, 16);
        }
        #pragma unroll
        for (int d = 0; d < 48; ++d)
            dstT[d * 40] = row[d];
        __syncthreads();

        bf16x8 af[3], bfr[3];
        #pragma unroll
        for (int mi = 0; mi < 3; ++mi)
            af[mi] = *(const bf16x8*)&kT[w][mi * 16 + r16][quad * 8];
        #pragma unroll
        for (int ni = 0; ni < 3; ++ni)
            bfr[ni] = *(const bf16x8*)&vT[w][ni * 16 + r16][quad * 8];
        #pragma unroll
        for (int mi = 0; mi < 3; ++mi)
            #pragma unroll
            for (int ni = 0; ni < 3; ++ni)
                acc[mi][ni] = __builtin_amdgcn_mfma_f32_16x16x32_bf16(af[mi], bfr[ni], acc[mi][ni], 0, 0, 0);
        __syncthreads();
    }

    #pragma unroll
    for (int mi = 0; mi < 3; ++mi)
        #pragma unroll
        for (int ni = 0; ni < 3; ++ni)
            #pragma unroll
            for (int reg = 0; reg < 4; ++reg)
                red[w][mi * 16 + quad * 4 + reg][ni * 16 + r16] = acc[mi][ni][reg];
    __syncthreads();

    float* Gb = G + (size_t)bh * 2304;
    for (int cell = t; cell < 2304; cell += 256) {
        int row = cell / 48, col = cell % 48;
        float s = red[0][row][col] + red[1][row][col] + red[2][row][col] + red[3][row][col];
        atomicAdd(&Gb[cell], s);
    }
}

// ---------------------------------------------------------------------------
// y[b,l,h*48+e] = sum_d q[b,h,l,d]*attn2[d,e] + lepe(v)  — MFMA version.
// scale_attn fused: attn2 computed in-block from G+sumsq+temp; blocks with
// blockIdx.x==0 also write attn_out (the second reference output).
// ---------------------------------------------------------------------------
__global__ __launch_bounds__(256) void qattn_lepe_mfma(
    const __hip_bfloat16* __restrict__ qkv, const float* __restrict__ G,
    const float* __restrict__ sumsq, const float* __restrict__ temp,
    const float* __restrict__ conv_w, const float* __restrict__ conv_b,
    __hip_bfloat16* __restrict__ y, float* __restrict__ attn_out)
{
    __shared__ __attribute__((aligned(16))) char smem[26624];
    __hip_bfloat16 (*qs)[72]  = (__hip_bfloat16 (*)[72])smem;            // [128][72]
    __hip_bfloat16 (*a2s)[72] = (__hip_bfloat16 (*)[72])(smem + 18432);  // [48][72]
    float (*ys)[52]           = (float (*)[52])smem;                     // [128][52]
    __shared__ __hip_bfloat16 vs[4][64][48];   // 24576 B
    __shared__ float cwT[9][48];
    __shared__ float cb[48];
    __shared__ float ink_s[48], inq_s[48];

    const int bh = blockIdx.y; const int b = bh >> 3; const int h = bh & 7;
    const int yi0 = blockIdx.x * 2;            // first image row of this block
    const int l0  = yi0 * 64;                  // first L index
    const int t = threadIdx.x;
    const int w = t >> 6, lane = t & 63;
    const int r16 = lane & 15, quad = lane >> 4;
    const float tf = temp[h];

    // ---- invnorms from sumsq (fused scale_attn) ----
    if (t < 48) {
        ink_s[t] = 1.f / fmaxf(sqrtf(sumsq[b * 768 + 384 + h * 48 + t]), 1e-12f);
        inq_s[t] = 1.f / fmaxf(sqrtf(sumsq[b * 768 +       h * 48 + t]), 1e-12f);
    }
    __syncthreads();

    const float* Gb = G + (size_t)bh * 2304;

    // ---- attn_out (reference output #2): one block per bh writes it ----
    if (blockIdx.x == 0) {
        for (int e = t; e < 2304; e += 256)
            attn_out[(size_t)bh * 2304 + e] = Gb[e] * ink_s[e / 48] * tf;
    }

    // ---- stage q tile (128 x 48, k-pad 48..63 = 0) ----
    const __hip_bfloat16* qbase = qkv + (size_t)(b * 4096 + l0) * 1152 + h * 48;
    #pragma unroll
    for (int i = 0; i < 3; ++i) {
        int chunk = t + i * 256;               // 768 chunks
        int row = chunk / 6, cg = chunk % 6;
        *(bf16x8*)&qs[row][cg * 8] = load8(qbase + (size_t)row * 1152 + cg * 8);
    }
    *(bf16x8*)&qs[t >> 1][48 + (t & 1) * 8] = (bf16x8)0;   // zero pad k 48..63

    // ---- stage attn2 transposed: a2s[e][d] = G[d,e]*ink[d]*tf*inq[d] ----
    for (int i = t; i < 3072; i += 256) {
        int e = i >> 6, dd = i & 63;
        float val = 0.f;
        if (dd < 48) {
            float av = Gb[dd * 48 + e] * ink_s[dd] * tf;
            val = av * inq_s[dd];
        }
        a2s[e][dd] = __float2bfloat16(val);
    }

    // ---- stage v image rows yi0-1 .. yi0+2 (zeros outside image) ----
    const __hip_bfloat16* vbase = qkv + (size_t)b * 4096 * 1152 + 768 + h * 48;
    #pragma unroll
    for (int i = 0; i < 6; ++i) {
        int chunk = t + i * 256;               // 1536 chunks
        int r = chunk / 384, rem = chunk % 384;
        int xx = rem / 6, cg = rem % 6;
        int yy = yi0 - 1 + r;
        bf16x8 v = (yy >= 0 && yy < 64)
            ? load8(vbase + (size_t)(yy * 64 + xx) * 1152 + cg * 8)
            : (bf16x8)0;
        *(bf16x8*)&vs[r][xx][cg * 8] = v;
    }

    // ---- conv weights (transposed) + bias ----
    for (int i = t; i < 432; i += 256)
        cwT[i / 48][i % 48] = conv_w[(h * 48 + (i % 48)) * 9 + (i / 48)];
    if (t < 48) cb[t] = conv_b[h * 48 + t];
    __syncthreads();

    // ---- MFMA: wave w computes rows w*32..w*32+31 ----
    f32x4 acc[2][3];
    #pragma unroll
    for (int mi = 0; mi < 2; ++mi)
        #pragma unroll
        for (int ni = 0; ni < 3; ++ni)
            acc[mi][ni] = (f32x4){0.f, 0.f, 0.f, 0.f};
    #pragma unroll
    for (int ks = 0; ks < 2; ++ks) {
        int kb = ks * 32 + quad * 8;
        bf16x8 af[2], bfr[3];
        #pragma unroll
        for (int mi = 0; mi < 2; ++mi)
            af[mi] = *(const bf16x8*)&qs[w * 32 + mi * 16 + r16][kb];
        #pragma unroll
        for (int ni = 0; ni < 3; ++ni)
            bfr[ni] = *(const bf16x8*)&a2s[ni * 16 + r16][kb];
        #pragma unroll
        for (int mi = 0; mi < 2; ++mi)
            #pragma unroll
            for (int ni = 0; ni < 3; ++ni)
                acc[mi][ni] = __builtin_amdgcn_mfma_f32_16x16x32_bf16(af[mi], bfr[ni], acc[mi][ni], 0, 0, 0);
    }
    __syncthreads();   // all waves done reading qs/a2s — safe to alias as ys

    // ---- write matmul result to ys (C/D layout: col=lane&15, row=quad*4+reg)
    #pragma unroll
    for (int mi = 0; mi < 2; ++mi)
        #pragma unroll
        for (int ni = 0; ni < 3; ++ni)
            #pragma unroll
            for (int reg = 0; reg < 4; ++reg)
                ys[w * 32 + mi * 16 + quad * 4 + reg][ni * 16 + r16] = acc[mi][ni][reg];
    __syncthreads();

    // ---- conv + bias + store (channel-vectorized, 8 ch per group) ----
    __hip_bfloat16* ybase = y + (size_t)(b * 4096 + l0) * 384 + h * 48;
    #pragma unroll
    for (int i = 0; i < 3; ++i) {
        int g = t + i * 256;                   // 768 groups
        int l_in = g / 6, cg = g % 6, e0 = cg * 8;
        int xi = l_in & 63, vr0 = l_in >> 6;   // local image col / base v-row
        float o[8];
        #pragma unroll
        for (int j = 0; j < 8; ++j) o[j] = ys[l_in][e0 + j] + cb[e0 + j];
        #pragma unroll
        for (int dy = 0; dy < 3; ++dy) {
            #pragma unroll
            for (int dx = 0; dx < 3; ++dx) {
                int xx = xi + dx - 1;
                if (xx < 0 || xx > 63) continue;
                bf16x8 vv = *(const bf16x8*)&vs[vr0 + dy][xx][e0];
                const float* cwp = &cwT[dy * 3 + dx][e0];
                #pragma unroll
                for (int j = 0; j < 8; ++j) o[j] += b2f(vv[j]) * cwp[j];
            }
        }
        __hip_bfloat16 ob[8];
        #pragma unroll
        for (int j = 0; j < 8; ++j) ob[j] = __float2bfloat16(o[j]);
        uint4 pk; __builtin_memcpy(&pk, ob, 16);
        *(uint4*)(ybase + (size_t)l_in * 384 + e0) = pk;
    }
}

// ---------------------------------------------------------------------------
extern "C" void kernel_launch(void* const* d_in, const int* in_sizes, int n_in,
                              void* d_out, int out_size, void* d_ws, size_t ws_size,
                              hipStream_t stream)
{
    const float* x      = (const float*)d_in[0];
    const float* qkv_w  = (const float*)d_in[1];
    const float* qkv_b  = (const float*)d_in[2];
    const float* proj_w = (const float*)d_in[3];
    const float* proj_b = (const float*)d_in[4];
    const float* temp   = (const float*)d_in[5];
    const float* conv_w = (const float*)d_in[6];
    const float* conv_b = (const float*)d_in[7];

    char* ws = (char*)d_ws;
    __hip_bfloat16* qkv = (__hip_bfloat16*)(ws);                 // 75,497,472 B
    __hip_bfloat16* yb  = (__hip_bfloat16*)(ws + 75497472);      // 25,165,824 B
    float* sumsq = (float*)(ws + 100663296);                     // 24,576 B
    float* G     = (float*)(ws + 100687872);                     // 589,824 B
    // x_bf16 aliases yb (dead until qattn_lepe); weight bf16 copies appended
    __hip_bfloat16* x_bf16  = yb;
    __hip_bfloat16* qkv_wb  = (__hip_bfloat16*)(ws + 101892096); // 884,736 B
    __hip_bfloat16* proj_wb = (__hip_bfloat16*)(ws + 102776832); // 294,912 B

    float* out      = (float*)d_out;
    float* attn_out = out + 12582912;

    // 0) convert x, qkv_w, proj_w to bf16; zero sumsq+G (fused memset)
    cvt_kernel<<<6582, 256, 0, stream>>>(x, x_bf16, qkv_w, qkv_wb, proj_w, proj_wb,
                                         (uint4*)(ws + 100663296));
    // 1) qkv = x @ qkv_w^T + qkv_b  (bf16 -> bf16), fused q/k column sumsq
    gemm_bf16_nt<__hip_bfloat16, 384, true><<<4608, 256, 0, stream>>>(
        x_bf16, qkv_wb, qkv_b, qkv, 1152, 18, sumsq);
    // 2) G = k^T v  (MFMA)
    ktv_mfma_kernel<<<dim3(16, 64), 256, 0, stream>>>(qkv, G);
    // 3) y = q @ attn2 + lepe   (MFMA, bf16 out — overwrites x_bf16 alias);
    //    attn2 computed in-block from G+sumsq; attn_out written by x==0 blocks
    qattn_lepe_mfma<<<dim3(32, 64), 256, 0, stream>>>(
        qkv, G, sumsq, temp, conv_w, conv_b, yb, attn_out);
    // 4) out = y @ proj_w^T + proj_b   (bf16 -> fp32)
    gemm_bf16_nt<float, 384, false><<<1536, 256, 0, stream>>>(
        yb, proj_wb, proj_b, out, 384, 6, nullptr);
}